// Round 11
// baseline (2890.956 us; speedup 1.0000x reference)
//
#include <hip/hip_runtime.h>

typedef __bf16 bf16x8 __attribute__((ext_vector_type(8)));
typedef float  f32x4  __attribute__((ext_vector_type(4)));
typedef short  s16x8  __attribute__((ext_vector_type(8)));
typedef unsigned int u32;
#define AS1 __attribute__((address_space(1)))
#define AS3 __attribute__((address_space(3)))

#define E_ 1024
#define T_ 1024
#define B_ 4
#define L_ 8
#define V_ 32000
#define M_ (B_*T_)   /* 4096 rows */

static __device__ __forceinline__ ushort f2bf(float f) {
  return __builtin_bit_cast(ushort, (__bf16)f);
}

// ---------------- weight cast f32 -> bf16 ----------------
__global__ __launch_bounds__(256) void castw_k(const float* __restrict__ in,
                                               ushort* __restrict__ out, int n) {
  int i = (blockIdx.x * 256 + threadIdx.x) * 8;
  if (i + 8 > n) return;
  float4 a = *(const float4*)(in + i);
  float4 b = *(const float4*)(in + i + 4);
  float v[8] = {a.x, a.y, a.z, a.w, b.x, b.y, b.z, b.w};
  union { s16x8 v; ushort u[8]; } pk;
  #pragma unroll
  for (int j = 0; j < 8; ++j) pk.u[j] = f2bf(v[j]);
  *(s16x8*)(out + i) = pk.v;
}

// ---------------- embedding ----------------
__global__ __launch_bounds__(256) void embed_k(const int* __restrict__ idx,
    const float* __restrict__ wte, const float* __restrict__ wpe,
    float* __restrict__ x) {
  int row = blockIdx.x;
  int tok = idx[row];
  int t = row & (T_ - 1);
  int c = threadIdx.x;
  float4 a = ((const float4*)(wte + (size_t)tok * E_))[c];
  float4 b = ((const float4*)(wpe + (size_t)t * E_))[c];
  float4 o; o.x = a.x + b.x; o.y = a.y + b.y; o.z = a.z + b.z; o.w = a.w + b.w;
  ((float4*)(x + (size_t)row * E_))[c] = o;
}

// ---------------- LN core ----------------
static __device__ __forceinline__ void ln_core(float4 v, int t,
    const float* __restrict__ w, const float* __restrict__ b,
    ushort* __restrict__ out, size_t row) {
  float s  = v.x + v.y + v.z + v.w;
  float s2 = v.x*v.x + v.y*v.y + v.z*v.z + v.w*v.w;
  #pragma unroll
  for (int o = 32; o > 0; o >>= 1) { s += __shfl_down(s, o); s2 += __shfl_down(s2, o); }
  __shared__ float sh[8];
  int wv = t >> 6;
  if ((t & 63) == 0) { sh[wv] = s; sh[4 + wv] = s2; }
  __syncthreads();
  s  = sh[0] + sh[1] + sh[2] + sh[3];
  s2 = sh[4] + sh[5] + sh[6] + sh[7];
  float mean = s * (1.f / E_);
  float var  = s2 * (1.f / E_) - mean * mean;
  float inv  = rsqrtf(var + 1e-5f);
  float4 wv4 = ((const float4*)w)[t];
  float4 bv4 = ((const float4*)b)[t];
  ushort* op = out + row * E_ + t * 4;
  op[0] = f2bf((v.x - mean) * inv * wv4.x + bv4.x);
  op[1] = f2bf((v.y - mean) * inv * wv4.y + bv4.y);
  op[2] = f2bf((v.z - mean) * inv * wv4.z + bv4.z);
  op[3] = f2bf((v.w - mean) * inv * wv4.w + bv4.w);
}

// ---------------- layernorm (f32 in, bf16 out) ----------------
__global__ __launch_bounds__(256) void ln_k(const float* __restrict__ x,
    const float* __restrict__ w, const float* __restrict__ b,
    ushort* __restrict__ out) {
  int row = blockIdx.x;
  int t = threadIdx.x;
  float4 v = ((const float4*)(x + (size_t)row * E_))[t];
  ln_core(v, t, w, b, out, (size_t)row);
}

// ---------------- split-K reduce + bias + residual + LN (fused) ----------------
__global__ __launch_bounds__(256) void redln_k(const float* __restrict__ p,
    const float* __restrict__ bias, float* __restrict__ x,
    const float* __restrict__ w, const float* __restrict__ b,
    ushort* __restrict__ out) {
  int row = blockIdx.x;
  int t = threadIdx.x;
  float4 v = ((const float4*)(x + (size_t)row * E_))[t];
  float4 bb = ((const float4*)bias)[t];
  v.x += bb.x; v.y += bb.y; v.z += bb.z; v.w += bb.w;
  #pragma unroll
  for (int sk = 0; sk < 4; ++sk) {
    float4 q = ((const float4*)(p + ((size_t)sk * M_ + row) * E_))[t];
    v.x += q.x; v.y += q.y; v.z += q.z; v.w += q.w;
  }
  ((float4*)(x + (size_t)row * E_))[t] = v;
  ln_core(v, t, w, b, out, (size_t)row);
}

// ======================================================================
// 256x256 GEMM, 2 phases/K-tile (B-dedup), ks-outer MFMA order.
// ======================================================================
#define BAR() do { __builtin_amdgcn_s_barrier(); __builtin_amdgcn_sched_barrier(0); } while (0)

template<int BUF, int SLOT, int RBV, int VM, typename F>
static __device__ __forceinline__ void phase2(
    const ushort (&AL)[32768], const ushort (&BL)[32768],
    bf16x8 (&av)[4][2], bf16x8 (&bv)[4][2],
    int arow, int brow, int ca0, int ca1, f32x4 (&acc)[8][4], F&& stage) {
  #pragma unroll
  for (int mfi = 0; mfi < 4; ++mfi) {
    av[mfi][0] = __builtin_bit_cast(bf16x8, *(const s16x8*)&AL[(BUF*2+SLOT)*8192 + arow + mfi*1024 + ca0]);
    av[mfi][1] = __builtin_bit_cast(bf16x8, *(const s16x8*)&AL[(BUF*2+SLOT)*8192 + arow + mfi*1024 + ca1]);
  }
  if (RBV) {
    #pragma unroll
    for (int nfi = 0; nfi < 2; ++nfi) {
      bv[nfi][0]     = __builtin_bit_cast(bf16x8, *(const s16x8*)&BL[(BUF*2+0)*8192 + brow + nfi*1024 + ca0]);
      bv[nfi][1]     = __builtin_bit_cast(bf16x8, *(const s16x8*)&BL[(BUF*2+0)*8192 + brow + nfi*1024 + ca1]);
      bv[2 + nfi][0] = __builtin_bit_cast(bf16x8, *(const s16x8*)&BL[(BUF*2+1)*8192 + brow + nfi*1024 + ca0]);
      bv[2 + nfi][1] = __builtin_bit_cast(bf16x8, *(const s16x8*)&BL[(BUF*2+1)*8192 + brow + nfi*1024 + ca1]);
    }
  }
  stage();
  BAR();
  __builtin_amdgcn_s_setprio(1);
  #pragma unroll
  for (int ks = 0; ks < 2; ++ks)
    #pragma unroll
    for (int mfi = 0; mfi < 4; ++mfi)
      #pragma unroll
      for (int nfi = 0; nfi < 4; ++nfi)
        acc[SLOT*4+mfi][nfi] = __builtin_amdgcn_mfma_f32_16x16x32_bf16(
            av[mfi][ks], bv[nfi][ks], acc[SLOT*4+mfi][nfi], 0, 0, 0);
  __builtin_amdgcn_s_setprio(0);
  if (VM) asm volatile("s_waitcnt vmcnt(4)");
  BAR();
}

#define GLDS(src, dst) __builtin_amdgcn_global_load_lds((const AS1 u32*)(src), (AS3 u32*)(dst), 16, 0, 0)
#define STAGE_A(b, s, t) do { \
  GLDS(ap##s##_0 + (size_t)(t)*64, &AL[((b)*2+(s))*8192 + w*512]); \
  GLDS(ap##s##_1 + (size_t)(t)*64, &AL[((b)*2+(s))*8192 + 4096 + w*512]); } while(0)
#define STAGE_B(b, s, t) do { \
  GLDS(bp##s##_0 + (size_t)(t)*64, &BL[((b)*2+(s))*8192 + w*512]); \
  GLDS(bp##s##_1 + (size_t)(t)*64, &BL[((b)*2+(s))*8192 + 4096 + w*512]); } while(0)

// EPI 0: outf=acc(+bias); 2: outh=gelu; 3: qkv coalesced scatter; 4: split-K partials.
template<int EPI>
static __device__ __forceinline__
void gemm8_body(const ushort* __restrict__ A, const ushort* __restrict__ W,
                const float* __restrict__ bias,
                float* __restrict__ outf, ushort* __restrict__ outh,
                ushort* __restrict__ qb, ushort* __restrict__ kb, ushort* __restrict__ vb,
                int M, int N, int K, int Kst) {
  __shared__ __align__(16) ushort AL[32768];
  __shared__ __align__(16) ushort BL[32768];
  int id  = blockIdx.x;
  int sk = 0, bx, by;
  if (EPI == 4) {            // split-K: grid = 4(bx) x 16(by) x 4(sk)
    sk = id >> 6; int rem = id & 63; bx = rem & 3; by = rem >> 2;
  } else {                   // XCD-chunked, bx-major (nwg%8==0, gy=16)
    int nwg = gridDim.x;
    int swz = (id & 7) * (nwg >> 3) + (id >> 3);
    bx = swz >> 4; by = swz & 15;
  }
  int bm = by * 256, bn = bx * 256;
  int tid = threadIdx.x;
  int w = tid >> 6, lane = tid & 63;
  int wm = w >> 2, wn = w & 3;
  int g = lane >> 4, lr = lane & 15;
  int sl8 = lane >> 3, sc = lane & 7;
  int cg8 = (sc ^ sl8) * 8;

  const ushort* Ab = A + (size_t)sk * K;
  const ushort* Wb = W + (size_t)sk * K;
  int r0 = w * 8 + sl8;
  const ushort* ap0_0 = Ab + (size_t)(bm +       0 + r0) * Kst + cg8;
  const ushort* ap0_1 = Ab + (size_t)(bm + 128 + 0 + r0) * Kst + cg8;
  const ushort* ap1_0 = Ab + (size_t)(bm +      64 + r0) * Kst + cg8;
  const ushort* ap1_1 = Ab + (size_t)(bm + 128 + 64 + r0) * Kst + cg8;
  int sr0 = r0, sr1 = 64 + r0;
  const ushort* bp0_0 = Wb + (size_t)(bn + (sr0 >> 5) * 64 +  0 + (sr0 & 31)) * Kst + cg8;
  const ushort* bp0_1 = Wb + (size_t)(bn + (sr1 >> 5) * 64 +  0 + (sr1 & 31)) * Kst + cg8;
  const ushort* bp1_0 = Wb + (size_t)(bn + (sr0 >> 5) * 64 + 32 + (sr0 & 31)) * Kst + cg8;
  const ushort* bp1_1 = Wb + (size_t)(bn + (sr1 >> 5) * 64 + 32 + (sr1 & 31)) * Kst + cg8;

  int NT = K >> 6;
  int NITER = NT >> 1;
  int arow = (wm * 64 + lr) * 64;
  int brow = (wn * 32 + lr) * 64;
  int ca0 = ((0 + g) ^ (lr & 7)) * 8;
  int ca1 = ((4 + g) ^ (lr & 7)) * 8;
  f32x4 acc[8][4] = {};
  bf16x8 av[4][2], bv[4][2];

  STAGE_A(0, 0, 0); STAGE_A(0, 1, 0); STAGE_B(0, 0, 0); STAGE_B(0, 1, 0);
  STAGE_A(1, 0, 1); STAGE_B(1, 0, 1);
  asm volatile("s_waitcnt vmcnt(0)" ::: "memory");
  BAR();

  for (int i = 0; i < NITER; ++i) {
    int t1 = 2 * i + 1;
    int t2 = 2 * i + 2; if (t2 > NT - 1) t2 = NT - 1;
    int t3 = 2 * i + 3; if (t3 > NT - 1) t3 = NT - 1;
    phase2<0,0,1,0>(AL, BL, av, bv, arow, brow, ca0, ca1, acc,
                    [&]{ STAGE_A(1, 1, t1); STAGE_B(1, 1, t1); });
    phase2<0,1,0,1>(AL, BL, av, bv, arow, brow, ca0, ca1, acc,
                    [&]{ STAGE_A(0, 0, t2); STAGE_B(0, 0, t2); });
    phase2<1,0,1,0>(AL, BL, av, bv, arow, brow, ca0, ca1, acc,
                    [&]{ STAGE_A(0, 1, t2); STAGE_B(0, 1, t2); });
    phase2<1,1,0,1>(AL, BL, av, bv, arow, brow, ca0, ca1, acc,
                    [&]{ STAGE_A(1, 0, t3); STAGE_B(1, 0, t3); });
  }

  ushort* dst = nullptr; float scl = 1.f;
  if (EPI == 3) {
    int sec = bn >> 10;
    dst = (sec == 0) ? qb : (sec == 1) ? kb : vb;
    scl = (sec == 0) ? 0.125f : 1.f;
  }
  #pragma unroll
  for (int mf = 0; mf < 8; ++mf) {
    #pragma unroll
    for (int reg = 0; reg < 4; ++reg) {
      int row = bm + wm * 128 + mf * 16 + g * 4 + reg;
      #pragma unroll
      for (int nf = 0; nf < 4; ++nf) {
        int col = bn + wn * 64 + nf * 16 + lr;
        float v = acc[mf][nf][reg];
        if (bias) v += bias[col];
        if (EPI == 0) {
          outf[(size_t)row * N + col] = v;
        } else if (EPI == 2) {
          float gl = 0.5f * v * (1.f + erff(v * 0.70710678118654752f));
          outh[(size_t)row * N + col] = f2bf(gl);
        } else if (EPI == 4) {
          outf[((size_t)sk * M + row) * N + col] = v;
        } else {
          int b = row >> 10, t = row & 1023;
          int cc = col & 1023;
          int h = cc >> 6, d = cc & 63;
          dst[((size_t)(b * 16 + h) * T_ + t) * 64 + d] = f2bf(v * scl);
        }
      }
    }
  }
}

__global__ __launch_bounds__(512, 2)
void gemm8_qkv(const ushort* A, const ushort* W, const float* bias,
               ushort* qb, ushort* kb, ushort* vb) {
  gemm8_body<3>(A, W, bias, nullptr, nullptr, qb, kb, vb, M_, 3 * E_, E_, E_);
}
__global__ __launch_bounds__(512, 2)
void gemm8_fc(const ushort* A, const ushort* W, const float* bias, ushort* outh) {
  gemm8_body<2>(A, W, bias, nullptr, outh, nullptr, nullptr, nullptr, M_, 4 * E_, E_, E_);
}
__global__ __launch_bounds__(512, 2)
void gemm8_lm(const ushort* A, const ushort* W, float* outf) {
  gemm8_body<0>(A, W, nullptr, outf, nullptr, nullptr, nullptr, nullptr, M_, V_, E_, E_);
}
__global__ __launch_bounds__(512, 2)
void gemm8_sk(const ushort* A, const ushort* W, float* pbuf) {
  gemm8_body<4>(A, W, nullptr, pbuf, nullptr, nullptr, nullptr, nullptr, M_, E_, E_, 4 * E_);
}

// ---------------- 128x128 GEMM (proj: residual epilogue) ----------------
__global__ __launch_bounds__(256)
void gbt_proj(const ushort* __restrict__ A, const ushort* __restrict__ W,
              const float* __restrict__ bias, const float* __restrict__ res,
              float* __restrict__ outf, int M, int N, int K) {
  __shared__ __align__(16) ushort As[128 * 32];
  __shared__ __align__(16) ushort Ws[128 * 32];
  int tid  = threadIdx.x;
  int bn   = blockIdx.x * 128;
  int bm   = blockIdx.y * 128;
  int wave = tid >> 6, lane = tid & 63;
  int wr = wave >> 1, wc = wave & 1;
  int g  = lane >> 4, lr = lane & 15;
  f32x4 acc[4][4] = {};
  int srow = lane >> 2;
  int scol = (lane & 3) * 8;
  const ushort* Abase = A + (size_t)bm * K;
  const ushort* Wbase = W + (size_t)bn * K;

  for (int k0 = 0; k0 < K; k0 += 32) {
    #pragma unroll
    for (int it = 0; it < 2; ++it) {
      int rb = (wave * 2 + it) * 16;
      __builtin_amdgcn_global_load_lds(
          (const AS1 u32*)(Abase + (size_t)(rb + srow) * K + k0 + scol),
          (AS3 u32*)&As[rb * 32], 16, 0, 0);
      __builtin_amdgcn_global_load_lds(
          (const AS1 u32*)(Wbase + (size_t)(rb + srow) * K + k0 + scol),
          (AS3 u32*)&Ws[rb * 32], 16, 0, 0);
    }
    __syncthreads();
    bf16x8 af[4], bfr[4];
    #pragma unroll
    for (int f = 0; f < 4; ++f) {
      af[f]  = __builtin_bit_cast(bf16x8, *(const s16x8*)&As[(wr * 64 + f * 16 + lr) * 32 + g * 8]);
      bfr[f] = __builtin_bit_cast(bf16x8, *(const s16x8*)&Ws[(wc * 64 + f * 16 + lr) * 32 + g * 8]);
    }
    #pragma unroll
    for (int mf = 0; mf < 4; ++mf)
      #pragma unroll
      for (int nf = 0; nf < 4; ++nf)
        acc[mf][nf] = __builtin_amdgcn_mfma_f32_16x16x32_bf16(af[mf], bfr[nf], acc[mf][nf], 0, 0, 0);
    __syncthreads();
  }

  #pragma unroll
  for (int mf = 0; mf < 4; ++mf) {
    #pragma unroll
    for (int reg = 0; reg < 4; ++reg) {
      int row = bm + wr * 64 + mf * 16 + g * 4 + reg;
      #pragma unroll
      for (int nf = 0; nf < 4; ++nf) {
        int col = bn + wc * 64 + nf * 16 + lr;
        float v = acc[mf][nf][reg] + bias[col];
        outf[(size_t)row * N + col] = v + res[(size_t)row * N + col];
      }
    }
  }
}

// ---------------- V transpose: [BH,T,64] -> [BH,64,T] ----------------
__global__ __launch_bounds__(256) void vtr_k(const ushort* __restrict__ vin,
                                             ushort* __restrict__ vout) {
  int bh = blockIdx.x, tt = blockIdx.y;
  __shared__ ushort ld[64 * 65];
  int tid = threadIdx.x;
  int row = tid >> 2;
  int cb  = (tid & 3) * 16;
  const ushort* src = vin + ((size_t)bh * T_ + tt * 64 + row) * 64 + cb;
  s16x8 va = *(const s16x8*)src;
  s16x8 vb = *(const s16x8*)(src + 8);
  #pragma unroll
  for (int i = 0; i < 8; ++i) ld[row * 65 + cb + i]     = (ushort)va[i];
  #pragma unroll
  for (int i = 0; i < 8; ++i) ld[row * 65 + cb + 8 + i] = (ushort)vb[i];
  __syncthreads();
  int d = row, tb = cb;
  union { s16x8 v[2]; ushort u[16]; } o;
  #pragma unroll
  for (int i = 0; i < 16; ++i) o.u[i] = ld[(tb + i) * 65 + d];
  ushort* dstp = vout + ((size_t)bh * 64 + d) * T_ + tt * 64 + tb;
  *(s16x8*)dstp = o.v[0];
  *(s16x8*)(dstp + 8) = o.v[1];
}

// ---------------- flash-decode attention: partial (O, m, l) per key-chunk ----------
// grid (64 bh, 32 qt, 4 chunk-of-256-keys), block 64 = 1 wave.
// Swapped QK^T (S^T = mfma(K,Q)); zero LDS; partials to pO/pml, merged by attnc_k.
static __device__ __forceinline__ void sm_step(
    f32x4 (&s)[4], float& m, float& l, f32x4 (&acc)[4], bf16x8 (&ap)[2],
    int qrow, int kbase0, bool diag, int g) {
  if (diag) {
    #pragma unroll
    for (int nf = 0; nf < 4; ++nf)
      #pragma unroll
      for (int reg = 0; reg < 4; ++reg)
        if (kbase0 + nf * 16 + g * 4 + reg > qrow) s[nf][reg] = -INFINITY;
  }
  float pmax = s[0][0];
  #pragma unroll
  for (int nf = 0; nf < 4; ++nf)
    #pragma unroll
    for (int reg = 0; reg < 4; ++reg) pmax = fmaxf(pmax, s[nf][reg]);
  pmax = fmaxf(pmax, __shfl_xor(pmax, 16));
  pmax = fmaxf(pmax, __shfl_xor(pmax, 32));
  if (__any(pmax > m + 8.f)) {        // defer-max rescale (THR=8)
    float mn = fmaxf(m, pmax);
    float corr = __expf(m - mn);
    m = mn; l *= corr;
    #pragma unroll
    for (int reg = 0; reg < 4; ++reg) {
      float cc = __shfl(corr, g * 4 + reg);
      #pragma unroll
      for (int nfd = 0; nfd < 4; ++nfd) acc[nfd][reg] *= cc;
    }
  }
  float ps = 0.f;
  union { bf16x8 v[2]; ushort u[16]; } pk;
  #pragma unroll
  for (int nf = 0; nf < 4; ++nf)
    #pragma unroll
    for (int reg = 0; reg < 4; ++reg) {
      float pv = __expf(s[nf][reg] - m);
      ps += pv;
      pk.u[nf * 4 + reg] = f2bf(pv);
    }
  ps += __shfl_xor(ps, 16);
  ps += __shfl_xor(ps, 32);
  l += ps;
  ap[0] = pk.v[0];
  ap[1] = pk.v[1];
}

__global__ __launch_bounds__(64) void attn_k(const ushort* __restrict__ Qg,
    const ushort* __restrict__ Kg, const ushort* __restrict__ Vg,
    float* __restrict__ pO, float* __restrict__ pml) {
  int bh = blockIdx.x;
  int qt = blockIdx.y;            // 0..31, 32 q-rows each
  int ch = blockIdx.z;            // key chunk of 256 (4 K-tiles)
  if (ch * 8 > qt) return;        // inactive chunk
  int lane = threadIdx.x;
  int g = lane >> 4, lr = lane & 15;
  int qbase = qt * 32;

  const ushort* kbase = Kg + (size_t)bh * T_ * 64;
  const ushort* vbase = Vg + (size_t)bh * 64 * T_;

  bf16x8 aq[2][2];
  #pragma unroll
  for (int st = 0; st < 2; ++st) {
    const ushort* qp = Qg + ((size_t)bh * T_ + qbase + st * 16 + lr) * 64;
    aq[st][0] = __builtin_bit_cast(bf16x8, *(const s16x8*)(qp + g * 8));
    aq[st][1] = __builtin_bit_cast(bf16x8, *(const s16x8*)(qp + 32 + g * 8));
  }

  f32x4 accO[2][4] = {};
  float m0 = -INFINITY, m1 = -INFINITY, l0 = 0.f, l1 = 0.f;

  int nkt = (qbase >> 6) + 1;     // total K-tiles for this q-tile
  int k0 = ch * 4;
  int kend = k0 + 4; if (kend > nkt) kend = nkt;
  for (int kt = k0; kt < kend; ++kt) {
    bool diag = (kt == nkt - 1);
    f32x4 s0[4] = {}, s1[4] = {};
    #pragma unroll
    for (int ks = 0; ks < 2; ++ks)
      #pragma unroll
      for (int nf = 0; nf < 4; ++nf) {
        bf16x8 ak = __builtin_bit_cast(bf16x8,
            *(const s16x8*)(kbase + (size_t)(kt * 64 + nf * 16 + lr) * 64 + ks * 32 + g * 8));
        s0[nf] = __builtin_amdgcn_mfma_f32_16x16x32_bf16(ak, aq[0][ks], s0[nf], 0, 0, 0);
        s1[nf] = __builtin_amdgcn_mfma_f32_16x16x32_bf16(ak, aq[1][ks], s1[nf], 0, 0, 0);
      }

    bf16x8 ap0[2], ap1[2];
    sm_step(s0, m0, l0, accO[0], ap0, qbase + 0 * 16 + lr, kt * 64, diag, g);
    sm_step(s1, m1, l1, accO[1], ap1, qbase + 1 * 16 + lr, kt * 64, diag, g);

    #pragma unroll
    for (int ks = 0; ks < 2; ++ks)
      #pragma unroll
      for (int nfd = 0; nfd < 4; ++nfd) {
        const ushort* vp = vbase + (size_t)(nfd * 16 + lr) * T_ + kt * 64 + ks * 32 + g * 4;
        uint2 vlo = *(const uint2*)vp;
        uint2 vhi = *(const uint2*)(vp + 16);
        union { uint4 u; bf16x8 v; } bb;
        bb.u = make_uint4(vlo.x, vlo.y, vhi.x, vhi.y);
        accO[0][nfd] = __builtin_amdgcn_mfma_f32_16x16x32_bf16(ap0[ks], bb.v, accO[0][nfd], 0, 0, 0);
        accO[1][nfd] = __builtin_amdgcn_mfma_f32_16x16x32_bf16(ap1[ks], bb.v, accO[1][nfd], 0, 0, 0);
      }
  }

  size_t idx = (size_t)(bh * 32 + qt) * 4 + ch;
  float* op = pO + idx * 2048;
  #pragma unroll
  for (int st = 0; st < 2; ++st)
    #pragma unroll
    for (int nfd = 0; nfd < 4; ++nfd)
      #pragma unroll
      for (int reg = 0; reg < 4; ++reg)
        op[(st * 16 + g * 4 + reg) * 64 + nfd * 16 + lr] = accO[st][nfd][reg];
  if (g == 0) {
    pml[idx * 64 +      0 + lr] = m0;
    pml[idx * 64 +     16 + lr] = m1;
    pml[idx * 64 + 32 + 0 + lr] = l0;
    pml[idx * 64 + 32 + 16 + lr] = l1;
  }
}

// ---------------- attention combine: merge chunk partials ----------------
// grid (64 bh, 32 qt), block 256. thread: row=t/8, 8 d's = (t%8)*8.
__global__ __launch_bounds__(256) void attnc_k(const float* __restrict__ pO,
    const float* __restrict__ pml, ushort* __restrict__ y) {
  int bh = blockIdx.x, qt = blockIdx.y;
  int b = bh >> 4, h = bh & 15;
  int nch = qt / 8 + 1;
  int tid = threadIdx.x;
  int row = tid >> 3, ds = (tid & 7) * 8;
  size_t base = (size_t)(bh * 32 + qt) * 4;
  // row index within pml: rows 0..15 at [0..15], 16..31 at [16..31] (m), +32 (l)
  float M = -INFINITY;
  for (int c = 0; c < nch; ++c)
    M = fmaxf(M, pml[(base + c) * 64 + row]);
  float L = 0.f;
  float acc[8] = {};
  for (int c = 0; c < nch; ++c) {
    float mc = pml[(base + c) * 64 + row];
    float lc = pml[(base + c) * 64 + 32 + row];
    float wgt = __expf(mc - M);
    L += lc * wgt;
    const float* op = pO + (base + c) * 2048 + row * 64 + ds;
    #pragma unroll
    for (int j = 0; j < 8; ++j) acc[j] += wgt * op[j];
  }
  float inv = 1.f / L;
  ushort* yp = y + ((size_t)b * T_ + qt * 32 + row) * E_ + h * 64 + ds;
  #pragma unroll
  for (int j = 0; j < 8; ++j) yp[j] = f2bf(acc[j] * inv);
}

// ---------------- orchestration ----------------
extern "C" void kernel_launch(void* const* d_in, const int* in_sizes, int n_in,
                              void* d_out, int out_size, void* d_ws, size_t ws_size,
                              hipStream_t stream) {
  const int*   idx   = (const int*)  d_in[0];
  const float* wte   = (const float*)d_in[1];
  const float* wpe   = (const float*)d_in[2];
  const float* ln1w  = (const float*)d_in[3];
  const float* ln1b  = (const float*)d_in[4];
  const float* attnw = (const float*)d_in[5];
  const float* attnb = (const float*)d_in[6];
  const float* projw = (const float*)d_in[7];
  const float* projb = (const float*)d_in[8];
  const float* ln2w  = (const float*)d_in[9];
  const float* ln2b  = (const float*)d_in[10];
  const float* fcw   = (const float*)d_in[11];
  const float* fcb   = (const float*)d_in[12];
  const float* fc2w  = (const float*)d_in[13];
  const float* fc2b  = (const float*)d_in[14];
  const float* lnfw  = (const float*)d_in[15];
  const float* lnfb  = (const float*)d_in[16];
  const float* lmw   = (const float*)d_in[17];
  float* out = (float*)d_out;

  char* p = (char*)d_ws;
  auto take = [&](size_t bytes) { char* r = p; p += (bytes + 255) & ~(size_t)255; return r; };
  ushort* wb_attn = (ushort*)take((size_t)L_ * 3 * E_ * E_ * 2);
  ushort* wb_proj = (ushort*)take((size_t)L_ * E_ * E_ * 2);
  ushort* wb_fc   = (ushort*)take((size_t)L_ * 4 * E_ * E_ * 2);
  ushort* wb_fc2  = (ushort*)take((size_t)L_ * E_ * 4 * E_ * 2);
  ushort* wb_lm   = (ushort*)take((size_t)V_ * E_ * 2);
  float*  x       = (float*) take((size_t)M_ * E_ * 4);
  ushort* hbuf    = (ushort*)take((size_t)M_ * E_ * 2);
  ushort* qb      = (ushort*)take((size_t)B_ * 16 * T_ * 64 * 2);
  ushort* kbuf    = (ushort*)take((size_t)B_ * 16 * T_ * 64 * 2);
  ushort* vbuf    = (ushort*)take((size_t)B_ * 16 * T_ * 64 * 2);
  ushort* vtb     = (ushort*)take((size_t)B_ * 16 * T_ * 64 * 2);
  ushort* ybuf    = (ushort*)take((size_t)M_ * E_ * 2);
  ushort* mlp     = (ushort*)take((size_t)M_ * 4 * E_ * 2);
  float*  pbuf    = (float*) take((size_t)4 * M_ * E_ * 4);   // fc2 partials; aliased as attn pO
  float*  pml     = (float*) take((size_t)64 * 32 * 4 * 64 * 4);

  castw_k<<<(L_ * 3 * E_ * E_) / 2048, 256, 0, stream>>>(attnw, wb_attn, L_ * 3 * E_ * E_);
  castw_k<<<(L_ * E_ * E_) / 2048, 256, 0, stream>>>(projw, wb_proj, L_ * E_ * E_);
  castw_k<<<(L_ * 4 * E_ * E_) / 2048, 256, 0, stream>>>(fcw, wb_fc, L_ * 4 * E_ * E_);
  castw_k<<<(L_ * E_ * 4 * E_) / 2048, 256, 0, stream>>>(fc2w, wb_fc2, L_ * E_ * 4 * E_);
  castw_k<<<(V_ * E_) / 2048, 256, 0, stream>>>(lmw, wb_lm, V_ * E_);
  embed_k<<<M_, 256, 0, stream>>>(idx, wte, wpe, x);
  ln_k<<<M_, 256, 0, stream>>>(x, ln1w, ln1b, hbuf);   // ln1 of layer 0

  for (int l = 0; l < L_; ++l) {
    gemm8_qkv<<<(3 * E_ / 256) * (M_ / 256), 512, 0, stream>>>(
        hbuf, wb_attn + (size_t)l * 3 * E_ * E_, attnb + l * 3 * E_, qb, kbuf, vbuf);
    vtr_k<<<dim3(B_ * 16, T_ / 64), 256, 0, stream>>>(vbuf, vtb);
    attn_k<<<dim3(B_ * 16, 32, 4), 64, 0, stream>>>(qb, kbuf, vtb, pbuf, pml);
    attnc_k<<<dim3(B_ * 16, 32), 256, 0, stream>>>(pbuf, pml, ybuf);
    gbt_proj<<<dim3(E_ / 128, M_ / 128), 256, 0, stream>>>(
        ybuf, wb_proj + (size_t)l * E_ * E_, projb + l * E_, x, x, M_, E_, E_);
    ln_k<<<M_, 256, 0, stream>>>(x, ln2w + l * E_, ln2b + l * E_, hbuf);
    gemm8_fc<<<(4 * E_ / 256) * (M_ / 256), 512, 0, stream>>>(
        hbuf, wb_fc + (size_t)l * 4 * E_ * E_, fcb + l * 4 * E_, mlp);
    gemm8_sk<<<256, 512, 0, stream>>>(mlp, wb_fc2 + (size_t)l * E_ * 4 * E_, pbuf);
    if (l < L_ - 1)
      redln_k<<<M_, 256, 0, stream>>>(pbuf, fc2b + l * E_, x,
                                      ln1w + (l + 1) * E_, ln1b + (l + 1) * E_, hbuf);
    else
      redln_k<<<M_, 256, 0, stream>>>(pbuf, fc2b + l * E_, x, lnfw, lnfb, hbuf);
  }
  gemm8_lm<<<(V_ / 256) * (M_ / 256), 512, 0, stream>>>(hbuf, wb_lm, out);
}

// Round 12
// 2734.802 us; speedup vs baseline: 1.0571x; 1.0571x over previous
//
#include <hip/hip_runtime.h>

typedef __bf16 bf16x8 __attribute__((ext_vector_type(8)));
typedef float  f32x4  __attribute__((ext_vector_type(4)));
typedef short  s16x8  __attribute__((ext_vector_type(8)));
typedef unsigned int u32;
#define AS1 __attribute__((address_space(1)))
#define AS3 __attribute__((address_space(3)))

#define E_ 1024
#define T_ 1024
#define B_ 4
#define L_ 8
#define V_ 32000
#define M_ (B_*T_)   /* 4096 rows */

static __device__ __forceinline__ ushort f2bf(float f) {
  return __builtin_bit_cast(ushort, (__bf16)f);
}

// ---------------- fused weight cast f32 -> bf16 (all 5 tensors, 1 dispatch) ------
// block ranges (2048 elems/block): attn 12288 | proj 4096 | fc 16384 | fc2 16384 | lm 16000
__global__ __launch_bounds__(256) void castall_k(
    const float* __restrict__ a0, const float* __restrict__ a1,
    const float* __restrict__ a2, const float* __restrict__ a3,
    const float* __restrict__ a4,
    ushort* __restrict__ o0, ushort* __restrict__ o1, ushort* __restrict__ o2,
    ushort* __restrict__ o3, ushort* __restrict__ o4) {
  int bid = blockIdx.x;
  const float* in; ushort* out; int base;
  if (bid < 12288)      { in = a0; out = o0; base = bid; }
  else if (bid < 16384) { in = a1; out = o1; base = bid - 12288; }
  else if (bid < 32768) { in = a2; out = o2; base = bid - 16384; }
  else if (bid < 49152) { in = a3; out = o3; base = bid - 32768; }
  else                  { in = a4; out = o4; base = bid - 49152; }
  size_t i = ((size_t)base * 256 + threadIdx.x) * 8;
  float4 a = *(const float4*)(in + i);
  float4 b = *(const float4*)(in + i + 4);
  float v[8] = {a.x, a.y, a.z, a.w, b.x, b.y, b.z, b.w};
  union { s16x8 v; ushort u[8]; } pk;
  #pragma unroll
  for (int j = 0; j < 8; ++j) pk.u[j] = f2bf(v[j]);
  *(s16x8*)(out + i) = pk.v;
}

// ---------------- LN core ----------------
static __device__ __forceinline__ void ln_core(float4 v, int t,
    const float* __restrict__ w, const float* __restrict__ b,
    ushort* __restrict__ out, size_t row) {
  float s  = v.x + v.y + v.z + v.w;
  float s2 = v.x*v.x + v.y*v.y + v.z*v.z + v.w*v.w;
  #pragma unroll
  for (int o = 32; o > 0; o >>= 1) { s += __shfl_down(s, o); s2 += __shfl_down(s2, o); }
  __shared__ float sh[8];
  int wv = t >> 6;
  if ((t & 63) == 0) { sh[wv] = s; sh[4 + wv] = s2; }
  __syncthreads();
  s  = sh[0] + sh[1] + sh[2] + sh[3];
  s2 = sh[4] + sh[5] + sh[6] + sh[7];
  float mean = s * (1.f / E_);
  float var  = s2 * (1.f / E_) - mean * mean;
  float inv  = rsqrtf(var + 1e-5f);
  float4 wv4 = ((const float4*)w)[t];
  float4 bv4 = ((const float4*)b)[t];
  ushort* op = out + row * E_ + t * 4;
  op[0] = f2bf((v.x - mean) * inv * wv4.x + bv4.x);
  op[1] = f2bf((v.y - mean) * inv * wv4.y + bv4.y);
  op[2] = f2bf((v.z - mean) * inv * wv4.z + bv4.z);
  op[3] = f2bf((v.w - mean) * inv * wv4.w + bv4.w);
}

// ---------------- embedding + ln1(layer0) fused ----------------
__global__ __launch_bounds__(256) void embedln_k(const int* __restrict__ idx,
    const float* __restrict__ wte, const float* __restrict__ wpe,
    const float* __restrict__ w, const float* __restrict__ b,
    float* __restrict__ x, ushort* __restrict__ out) {
  int row = blockIdx.x;
  int tok = idx[row];
  int t = row & (T_ - 1);
  int c = threadIdx.x;
  float4 a = ((const float4*)(wte + (size_t)tok * E_))[c];
  float4 p = ((const float4*)(wpe + (size_t)t * E_))[c];
  float4 v; v.x = a.x + p.x; v.y = a.y + p.y; v.z = a.z + p.z; v.w = a.w + p.w;
  ((float4*)(x + (size_t)row * E_))[c] = v;
  ln_core(v, c, w, b, out, (size_t)row);
}

// ---------------- layernorm (f32 in, bf16 out) ----------------
__global__ __launch_bounds__(256) void ln_k(const float* __restrict__ x,
    const float* __restrict__ w, const float* __restrict__ b,
    ushort* __restrict__ out) {
  int row = blockIdx.x;
  int t = threadIdx.x;
  float4 v = ((const float4*)(x + (size_t)row * E_))[t];
  ln_core(v, t, w, b, out, (size_t)row);
}

// ---------------- split-K reduce + bias + residual + LN (fused) ----------------
__global__ __launch_bounds__(256) void redln_k(const float* __restrict__ p,
    const float* __restrict__ bias, float* __restrict__ x,
    const float* __restrict__ w, const float* __restrict__ b,
    ushort* __restrict__ out) {
  int row = blockIdx.x;
  int t = threadIdx.x;
  float4 v = ((const float4*)(x + (size_t)row * E_))[t];
  float4 bb = ((const float4*)bias)[t];
  v.x += bb.x; v.y += bb.y; v.z += bb.z; v.w += bb.w;
  #pragma unroll
  for (int sk = 0; sk < 4; ++sk) {
    float4 q = ((const float4*)(p + ((size_t)sk * M_ + row) * E_))[t];
    v.x += q.x; v.y += q.y; v.z += q.z; v.w += q.w;
  }
  ((float4*)(x + (size_t)row * E_))[t] = v;
  ln_core(v, t, w, b, out, (size_t)row);
}

// ======================================================================
// 256x256 GEMM, 2 phases/K-tile (B-dedup), ks-outer MFMA order.
// ======================================================================
#define BAR() do { __builtin_amdgcn_s_barrier(); __builtin_amdgcn_sched_barrier(0); } while (0)

template<int BUF, int SLOT, int RBV, int VM, typename F>
static __device__ __forceinline__ void phase2(
    const ushort (&AL)[32768], const ushort (&BL)[32768],
    bf16x8 (&av)[4][2], bf16x8 (&bv)[4][2],
    int arow, int brow, int ca0, int ca1, f32x4 (&acc)[8][4], F&& stage) {
  #pragma unroll
  for (int mfi = 0; mfi < 4; ++mfi) {
    av[mfi][0] = __builtin_bit_cast(bf16x8, *(const s16x8*)&AL[(BUF*2+SLOT)*8192 + arow + mfi*1024 + ca0]);
    av[mfi][1] = __builtin_bit_cast(bf16x8, *(const s16x8*)&AL[(BUF*2+SLOT)*8192 + arow + mfi*1024 + ca1]);
  }
  if (RBV) {
    #pragma unroll
    for (int nfi = 0; nfi < 2; ++nfi) {
      bv[nfi][0]     = __builtin_bit_cast(bf16x8, *(const s16x8*)&BL[(BUF*2+0)*8192 + brow + nfi*1024 + ca0]);
      bv[nfi][1]     = __builtin_bit_cast(bf16x8, *(const s16x8*)&BL[(BUF*2+0)*8192 + brow + nfi*1024 + ca1]);
      bv[2 + nfi][0] = __builtin_bit_cast(bf16x8, *(const s16x8*)&BL[(BUF*2+1)*8192 + brow + nfi*1024 + ca0]);
      bv[2 + nfi][1] = __builtin_bit_cast(bf16x8, *(const s16x8*)&BL[(BUF*2+1)*8192 + brow + nfi*1024 + ca1]);
    }
  }
  stage();
  BAR();
  __builtin_amdgcn_s_setprio(1);
  #pragma unroll
  for (int ks = 0; ks < 2; ++ks)
    #pragma unroll
    for (int mfi = 0; mfi < 4; ++mfi)
      #pragma unroll
      for (int nfi = 0; nfi < 4; ++nfi)
        acc[SLOT*4+mfi][nfi] = __builtin_amdgcn_mfma_f32_16x16x32_bf16(
            av[mfi][ks], bv[nfi][ks], acc[SLOT*4+mfi][nfi], 0, 0, 0);
  __builtin_amdgcn_s_setprio(0);
  if (VM) asm volatile("s_waitcnt vmcnt(4)");
  BAR();
}

#define GLDS(src, dst) __builtin_amdgcn_global_load_lds((const AS1 u32*)(src), (AS3 u32*)(dst), 16, 0, 0)
#define STAGE_A(b, s, t) do { \
  GLDS(ap##s##_0 + (size_t)(t)*64, &AL[((b)*2+(s))*8192 + w*512]); \
  GLDS(ap##s##_1 + (size_t)(t)*64, &AL[((b)*2+(s))*8192 + 4096 + w*512]); } while(0)
#define STAGE_B(b, s, t) do { \
  GLDS(bp##s##_0 + (size_t)(t)*64, &BL[((b)*2+(s))*8192 + w*512]); \
  GLDS(bp##s##_1 + (size_t)(t)*64, &BL[((b)*2+(s))*8192 + 4096 + w*512]); } while(0)

// EPI 0: outf=acc(+bias); 2: outh=gelu; 3: qkv scatter (V transposed); 4: split-K partials.
template<int EPI>
static __device__ __forceinline__
void gemm8_body(const ushort* __restrict__ A, const ushort* __restrict__ W,
                const float* __restrict__ bias,
                float* __restrict__ outf, ushort* __restrict__ outh,
                ushort* __restrict__ qb, ushort* __restrict__ kb, ushort* __restrict__ vb,
                int M, int N, int K, int Kst) {
  __shared__ __align__(16) ushort AL[32768];
  __shared__ __align__(16) ushort BL[32768];
  int id  = blockIdx.x;
  int sk = 0, bx, by;
  if (EPI == 4) {            // split-K: grid = 4(bx) x 16(by) x 4(sk)
    sk = id >> 6; int rem = id & 63; bx = rem & 3; by = rem >> 2;
  } else {                   // XCD-chunked, bx-major (nwg%8==0, gy=16)
    int nwg = gridDim.x;
    int swz = (id & 7) * (nwg >> 3) + (id >> 3);
    bx = swz >> 4; by = swz & 15;
  }
  int bm = by * 256, bn = bx * 256;
  int tid = threadIdx.x;
  int w = tid >> 6, lane = tid & 63;
  int wm = w >> 2, wn = w & 3;
  int g = lane >> 4, lr = lane & 15;
  int sl8 = lane >> 3, sc = lane & 7;
  int cg8 = (sc ^ sl8) * 8;

  const ushort* Ab = A + (size_t)sk * K;
  const ushort* Wb = W + (size_t)sk * K;
  int r0 = w * 8 + sl8;
  const ushort* ap0_0 = Ab + (size_t)(bm +       0 + r0) * Kst + cg8;
  const ushort* ap0_1 = Ab + (size_t)(bm + 128 + 0 + r0) * Kst + cg8;
  const ushort* ap1_0 = Ab + (size_t)(bm +      64 + r0) * Kst + cg8;
  const ushort* ap1_1 = Ab + (size_t)(bm + 128 + 64 + r0) * Kst + cg8;
  int sr0 = r0, sr1 = 64 + r0;
  const ushort* bp0_0 = Wb + (size_t)(bn + (sr0 >> 5) * 64 +  0 + (sr0 & 31)) * Kst + cg8;
  const ushort* bp0_1 = Wb + (size_t)(bn + (sr1 >> 5) * 64 +  0 + (sr1 & 31)) * Kst + cg8;
  const ushort* bp1_0 = Wb + (size_t)(bn + (sr0 >> 5) * 64 + 32 + (sr0 & 31)) * Kst + cg8;
  const ushort* bp1_1 = Wb + (size_t)(bn + (sr1 >> 5) * 64 + 32 + (sr1 & 31)) * Kst + cg8;

  int NT = K >> 6;
  int NITER = NT >> 1;
  int arow = (wm * 64 + lr) * 64;
  int brow = (wn * 32 + lr) * 64;
  int ca0 = ((0 + g) ^ (lr & 7)) * 8;
  int ca1 = ((4 + g) ^ (lr & 7)) * 8;
  f32x4 acc[8][4] = {};
  bf16x8 av[4][2], bv[4][2];

  STAGE_A(0, 0, 0); STAGE_A(0, 1, 0); STAGE_B(0, 0, 0); STAGE_B(0, 1, 0);
  STAGE_A(1, 0, 1); STAGE_B(1, 0, 1);
  asm volatile("s_waitcnt vmcnt(0)" ::: "memory");
  BAR();

  for (int i = 0; i < NITER; ++i) {
    int t1 = 2 * i + 1;
    int t2 = 2 * i + 2; if (t2 > NT - 1) t2 = NT - 1;
    int t3 = 2 * i + 3; if (t3 > NT - 1) t3 = NT - 1;
    phase2<0,0,1,0>(AL, BL, av, bv, arow, brow, ca0, ca1, acc,
                    [&]{ STAGE_A(1, 1, t1); STAGE_B(1, 1, t1); });
    phase2<0,1,0,1>(AL, BL, av, bv, arow, brow, ca0, ca1, acc,
                    [&]{ STAGE_A(0, 0, t2); STAGE_B(0, 0, t2); });
    phase2<1,0,1,0>(AL, BL, av, bv, arow, brow, ca0, ca1, acc,
                    [&]{ STAGE_A(0, 1, t2); STAGE_B(0, 1, t2); });
    phase2<1,1,0,1>(AL, BL, av, bv, arow, brow, ca0, ca1, acc,
                    [&]{ STAGE_A(1, 0, t3); STAGE_B(1, 0, t3); });
  }

  if (EPI == 3 && (bn >> 10) == 2) {
    // V section: fused transpose store. Thread owns 4 consecutive t per (mf,nf).
    #pragma unroll
    for (int mf = 0; mf < 8; ++mf) {
      int row = bm + wm * 128 + mf * 16 + g * 4;
      int b = row >> 10, t = row & 1023;
      #pragma unroll
      for (int nf = 0; nf < 4; ++nf) {
        int col = bn + wn * 64 + nf * 16 + lr;
        int cc = col & 1023;
        int h = cc >> 6, d = cc & 63;
        float bs = bias[col];
        union { ushort u[4]; uint2 v; } pk4;
        #pragma unroll
        for (int reg = 0; reg < 4; ++reg) pk4.u[reg] = f2bf(acc[mf][nf][reg] + bs);
        *(uint2*)&vb[((size_t)(b * 16 + h) * 64 + d) * T_ + t] = pk4.v;
      }
    }
    return;
  }

  ushort* dst = nullptr; float scl = 1.f;
  if (EPI == 3) {
    int sec = bn >> 10;
    dst = (sec == 0) ? qb : kb;
    scl = (sec == 0) ? 0.125f : 1.f;
  }
  #pragma unroll
  for (int mf = 0; mf < 8; ++mf) {
    #pragma unroll
    for (int reg = 0; reg < 4; ++reg) {
      int row = bm + wm * 128 + mf * 16 + g * 4 + reg;
      #pragma unroll
      for (int nf = 0; nf < 4; ++nf) {
        int col = bn + wn * 64 + nf * 16 + lr;
        float v = acc[mf][nf][reg];
        if (bias) v += bias[col];
        if (EPI == 0) {
          outf[(size_t)row * N + col] = v;
        } else if (EPI == 2) {
          float gl = 0.5f * v * (1.f + erff(v * 0.70710678118654752f));
          outh[(size_t)row * N + col] = f2bf(gl);
        } else if (EPI == 4) {
          outf[((size_t)sk * M + row) * N + col] = v;
        } else {
          int b = row >> 10, t = row & 1023;
          int cc = col & 1023;
          int h = cc >> 6, d = cc & 63;
          dst[((size_t)(b * 16 + h) * T_ + t) * 64 + d] = f2bf(v * scl);
        }
      }
    }
  }
}

__global__ __launch_bounds__(512, 2)
void gemm8_qkv(const ushort* A, const ushort* W, const float* bias,
               ushort* qb, ushort* kb, ushort* vtb) {
  gemm8_body<3>(A, W, bias, nullptr, nullptr, qb, kb, vtb, M_, 3 * E_, E_, E_);
}
__global__ __launch_bounds__(512, 2)
void gemm8_fc(const ushort* A, const ushort* W, const float* bias, ushort* outh) {
  gemm8_body<2>(A, W, bias, nullptr, outh, nullptr, nullptr, nullptr, M_, 4 * E_, E_, E_);
}
__global__ __launch_bounds__(512, 2)
void gemm8_lm(const ushort* A, const ushort* W, float* outf) {
  gemm8_body<0>(A, W, nullptr, outf, nullptr, nullptr, nullptr, nullptr, M_, V_, E_, E_);
}
__global__ __launch_bounds__(512, 2)
void gemm8_sk(const ushort* A, const ushort* W, float* pbuf) {
  gemm8_body<4>(A, W, nullptr, pbuf, nullptr, nullptr, nullptr, nullptr, M_, E_, E_, 4 * E_);
}

// ---------------- 128x128 GEMM (proj: residual epilogue) ----------------
__global__ __launch_bounds__(256)
void gbt_proj(const ushort* __restrict__ A, const ushort* __restrict__ W,
              const float* __restrict__ bias, const float* __restrict__ res,
              float* __restrict__ outf, int M, int N, int K) {
  __shared__ __align__(16) ushort As[128 * 32];
  __shared__ __align__(16) ushort Ws[128 * 32];
  int tid  = threadIdx.x;
  int bn   = blockIdx.x * 128;
  int bm   = blockIdx.y * 128;
  int wave = tid >> 6, lane = tid & 63;
  int wr = wave >> 1, wc = wave & 1;
  int g  = lane >> 4, lr = lane & 15;
  f32x4 acc[4][4] = {};
  int srow = lane >> 2;
  int scol = (lane & 3) * 8;
  const ushort* Abase = A + (size_t)bm * K;
  const ushort* Wbase = W + (size_t)bn * K;

  for (int k0 = 0; k0 < K; k0 += 32) {
    #pragma unroll
    for (int it = 0; it < 2; ++it) {
      int rb = (wave * 2 + it) * 16;
      __builtin_amdgcn_global_load_lds(
          (const AS1 u32*)(Abase + (size_t)(rb + srow) * K + k0 + scol),
          (AS3 u32*)&As[rb * 32], 16, 0, 0);
      __builtin_amdgcn_global_load_lds(
          (const AS1 u32*)(Wbase + (size_t)(rb + srow) * K + k0 + scol),
          (AS3 u32*)&Ws[rb * 32], 16, 0, 0);
    }
    __syncthreads();
    bf16x8 af[4], bfr[4];
    #pragma unroll
    for (int f = 0; f < 4; ++f) {
      af[f]  = __builtin_bit_cast(bf16x8, *(const s16x8*)&As[(wr * 64 + f * 16 + lr) * 32 + g * 8]);
      bfr[f] = __builtin_bit_cast(bf16x8, *(const s16x8*)&Ws[(wc * 64 + f * 16 + lr) * 32 + g * 8]);
    }
    #pragma unroll
    for (int mf = 0; mf < 4; ++mf)
      #pragma unroll
      for (int nf = 0; nf < 4; ++nf)
        acc[mf][nf] = __builtin_amdgcn_mfma_f32_16x16x32_bf16(af[mf], bfr[nf], acc[mf][nf], 0, 0, 0);
    __syncthreads();
  }

  #pragma unroll
  for (int mf = 0; mf < 4; ++mf) {
    #pragma unroll
    for (int reg = 0; reg < 4; ++reg) {
      int row = bm + wr * 64 + mf * 16 + g * 4 + reg;
      #pragma unroll
      for (int nf = 0; nf < 4; ++nf) {
        int col = bn + wc * 64 + nf * 16 + lr;
        float v = acc[mf][nf][reg] + bias[col];
        outf[(size_t)row * N + col] = v + res[(size_t)row * N + col];
      }
    }
  }
}

// ---------------- MFMA flash attention, swapped-QK^T, zero-LDS, 1-wave blocks --------
static __device__ __forceinline__ void sm_step(
    f32x4 (&s)[4], float& m, float& l, f32x4 (&acc)[4], bf16x8 (&ap)[2],
    int qrow, int kbase0, bool diag, int g) {
  if (diag) {
    #pragma unroll
    for (int nf = 0; nf < 4; ++nf)
      #pragma unroll
      for (int reg = 0; reg < 4; ++reg)
        if (kbase0 + nf * 16 + g * 4 + reg > qrow) s[nf][reg] = -INFINITY;
  }
  float pmax = s[0][0];
  #pragma unroll
  for (int nf = 0; nf < 4; ++nf)
    #pragma unroll
    for (int reg = 0; reg < 4; ++reg) pmax = fmaxf(pmax, s[nf][reg]);
  pmax = fmaxf(pmax, __shfl_xor(pmax, 16));
  pmax = fmaxf(pmax, __shfl_xor(pmax, 32));
  if (__any(pmax > m + 8.f)) {        // defer-max rescale (THR=8)
    float mn = fmaxf(m, pmax);
    float corr = __expf(m - mn);
    m = mn; l *= corr;
    #pragma unroll
    for (int reg = 0; reg < 4; ++reg) {
      float cc = __shfl(corr, g * 4 + reg);
      #pragma unroll
      for (int nfd = 0; nfd < 4; ++nfd) acc[nfd][reg] *= cc;
    }
  }
  float ps = 0.f;
  union { bf16x8 v[2]; ushort u[16]; } pk;
  #pragma unroll
  for (int nf = 0; nf < 4; ++nf)
    #pragma unroll
    for (int reg = 0; reg < 4; ++reg) {
      float pv = __expf(s[nf][reg] - m);
      ps += pv;
      pk.u[nf * 4 + reg] = f2bf(pv);
    }
  ps += __shfl_xor(ps, 16);
  ps += __shfl_xor(ps, 32);
  l += ps;
  ap[0] = pk.v[0];
  ap[1] = pk.v[1];
}

__global__ __launch_bounds__(64) void attn_k(const ushort* __restrict__ Qg,
    const ushort* __restrict__ Kg, const ushort* __restrict__ Vg,
    ushort* __restrict__ y) {
  int bh = blockIdx.x;
  int qt = blockIdx.y;            // 0..31, 32 q-rows each
  int lane = threadIdx.x;
  int g = lane >> 4, lr = lane & 15;
  int qbase = qt * 32;

  const ushort* kbase = Kg + (size_t)bh * T_ * 64;
  const ushort* vbase = Vg + (size_t)bh * 64 * T_;

  bf16x8 aq[2][2];
  #pragma unroll
  for (int st = 0; st < 2; ++st) {
    const ushort* qp = Qg + ((size_t)bh * T_ + qbase + st * 16 + lr) * 64;
    aq[st][0] = __builtin_bit_cast(bf16x8, *(const s16x8*)(qp + g * 8));
    aq[st][1] = __builtin_bit_cast(bf16x8, *(const s16x8*)(qp + 32 + g * 8));
  }

  f32x4 accO[2][4] = {};
  float m0 = -INFINITY, m1 = -INFINITY, l0 = 0.f, l1 = 0.f;

  int nkt = (qbase >> 6) + 1;
  for (int kt = 0; kt < nkt; ++kt) {
    bool diag = (kt == nkt - 1);
    f32x4 s0[4] = {}, s1[4] = {};
    #pragma unroll
    for (int ks = 0; ks < 2; ++ks)
      #pragma unroll
      for (int nf = 0; nf < 4; ++nf) {
        bf16x8 ak = __builtin_bit_cast(bf16x8,
            *(const s16x8*)(kbase + (size_t)(kt * 64 + nf * 16 + lr) * 64 + ks * 32 + g * 8));
        s0[nf] = __builtin_amdgcn_mfma_f32_16x16x32_bf16(ak, aq[0][ks], s0[nf], 0, 0, 0);
        s1[nf] = __builtin_amdgcn_mfma_f32_16x16x32_bf16(ak, aq[1][ks], s1[nf], 0, 0, 0);
      }

    bf16x8 ap0[2], ap1[2];
    sm_step(s0, m0, l0, accO[0], ap0, qbase + 0 * 16 + lr, kt * 64, diag, g);
    sm_step(s1, m1, l1, accO[1], ap1, qbase + 1 * 16 + lr, kt * 64, diag, g);

    #pragma unroll
    for (int ks = 0; ks < 2; ++ks)
      #pragma unroll
      for (int nfd = 0; nfd < 4; ++nfd) {
        const ushort* vp = vbase + (size_t)(nfd * 16 + lr) * T_ + kt * 64 + ks * 32 + g * 4;
        uint2 vlo = *(const uint2*)vp;
        uint2 vhi = *(const uint2*)(vp + 16);
        union { uint4 u; bf16x8 v; } bb;
        bb.u = make_uint4(vlo.x, vlo.y, vhi.x, vhi.y);
        accO[0][nfd] = __builtin_amdgcn_mfma_f32_16x16x32_bf16(ap0[ks], bb.v, accO[0][nfd], 0, 0, 0);
        accO[1][nfd] = __builtin_amdgcn_mfma_f32_16x16x32_bf16(ap1[ks], bb.v, accO[1][nfd], 0, 0, 0);
      }
  }

  int b = bh >> 4, h = bh & 15;
  float li0 = 1.f / l0, li1 = 1.f / l1;
  #pragma unroll
  for (int st = 0; st < 2; ++st) {
    float lsrc = (st == 0) ? li0 : li1;
    #pragma unroll
    for (int reg = 0; reg < 4; ++reg) {
      float inv = __shfl(lsrc, g * 4 + reg);
      size_t row = (size_t)b * T_ + qbase + st * 16 + g * 4 + reg;
      #pragma unroll
      for (int nfd = 0; nfd < 4; ++nfd)
        y[row * E_ + h * 64 + nfd * 16 + lr] = f2bf(accO[st][nfd][reg] * inv);
    }
  }
}

// ---------------- orchestration ----------------
extern "C" void kernel_launch(void* const* d_in, const int* in_sizes, int n_in,
                              void* d_out, int out_size, void* d_ws, size_t ws_size,
                              hipStream_t stream) {
  const int*   idx   = (const int*)  d_in[0];
  const float* wte   = (const float*)d_in[1];
  const float* wpe   = (const float*)d_in[2];
  const float* ln1w  = (const float*)d_in[3];
  const float* ln1b  = (const float*)d_in[4];
  const float* attnw = (const float*)d_in[5];
  const float* attnb = (const float*)d_in[6];
  const float* projw = (const float*)d_in[7];
  const float* projb = (const float*)d_in[8];
  const float* ln2w  = (const float*)d_in[9];
  const float* ln2b  = (const float*)d_in[10];
  const float* fcw   = (const float*)d_in[11];
  const float* fcb   = (const float*)d_in[12];
  const float* fc2w  = (const float*)d_in[13];
  const float* fc2b  = (const float*)d_in[14];
  const float* lnfw  = (const float*)d_in[15];
  const float* lnfb  = (const float*)d_in[16];
  const float* lmw   = (const float*)d_in[17];
  float* out = (float*)d_out;

  char* p = (char*)d_ws;
  auto take = [&](size_t bytes) { char* r = p; p += (bytes + 255) & ~(size_t)255; return r; };
  ushort* wb_attn = (ushort*)take((size_t)L_ * 3 * E_ * E_ * 2);
  ushort* wb_proj = (ushort*)take((size_t)L_ * E_ * E_ * 2);
  ushort* wb_fc   = (ushort*)take((size_t)L_ * 4 * E_ * E_ * 2);
  ushort* wb_fc2  = (ushort*)take((size_t)L_ * E_ * 4 * E_ * 2);
  ushort* wb_lm   = (ushort*)take((size_t)V_ * E_ * 2);
  float*  x       = (float*) take((size_t)M_ * E_ * 4);
  ushort* hbuf    = (ushort*)take((size_t)M_ * E_ * 2);
  ushort* qb      = (ushort*)take((size_t)B_ * 16 * T_ * 64 * 2);
  ushort* kbuf    = (ushort*)take((size_t)B_ * 16 * T_ * 64 * 2);
  ushort* vtb     = (ushort*)take((size_t)B_ * 16 * T_ * 64 * 2);
  ushort* ybuf    = (ushort*)take((size_t)M_ * E_ * 2);
  ushort* mlp     = (ushort*)take((size_t)M_ * 4 * E_ * 2);
  float*  pbuf    = (float*) take((size_t)4 * M_ * E_ * 4);

  castall_k<<<65152, 256, 0, stream>>>(attnw, projw, fcw, fc2w, lmw,
                                       wb_attn, wb_proj, wb_fc, wb_fc2, wb_lm);
  embedln_k<<<M_, 256, 0, stream>>>(idx, wte, wpe, ln1w, ln1b, x, hbuf);

  for (int l = 0; l < L_; ++l) {
    gemm8_qkv<<<(3 * E_ / 256) * (M_ / 256), 512, 0, stream>>>(
        hbuf, wb_attn + (size_t)l * 3 * E_ * E_, attnb + l * 3 * E_, qb, kbuf, vtb);
    attn_k<<<dim3(B_ * 16, 32), 64, 0, stream>>>(qb, kbuf, vtb, ybuf);
    gbt_proj<<<dim3(E_ / 128, M_ / 128), 256, 0, stream>>>(
        ybuf, wb_proj + (size_t)l * E_ * E_, projb + l * E_, x, x, M_, E_, E_);
    ln_k<<<M_, 256, 0, stream>>>(x, ln2w + l * E_, ln2b + l * E_, hbuf);
    gemm8_fc<<<(4 * E_ / 256) * (M_ / 256), 512, 0, stream>>>(
        hbuf, wb_fc + (size_t)l * 4 * E_ * E_, fcb + l * 4 * E_, mlp);
    gemm8_sk<<<256, 512, 0, stream>>>(mlp, wb_fc2 + (size_t)l * E_ * 4 * E_, pbuf);
    if (l < L_ - 1)
      redln_k<<<M_, 256, 0, stream>>>(pbuf, fc2b + l * E_, x,
                                      ln1w + (l + 1) * E_, ln1b + (l + 1) * E_, hbuf);
    else
      redln_k<<<M_, 256, 0, stream>>>(pbuf, fc2b + l * E_, x, lnfw, lnfb, hbuf);
  }
  gemm8_lm<<<(V_ / 256) * (M_ / 256), 512, 0, stream>>>(hbuf, wb_lm, out);
}